// Round 6
// baseline (439.761 us; speedup 1.0000x reference)
//
#include <hip/hip_runtime.h>
#include <math.h>

typedef __attribute__((ext_vector_type(8))) short short8;
typedef __attribute__((ext_vector_type(4))) float floatx4;

#define SQ 2048
#define NH 16
#define HD 128
#define NB 2
#define DM 2048
#define QKV_N 6144

__device__ __forceinline__ unsigned short f2bf(float f) {
  unsigned int x = __builtin_bit_cast(unsigned int, f);
  unsigned int r = x + 0x7fffu + ((x >> 16) & 1u);
  return (unsigned short)(r >> 16);
}
__device__ __forceinline__ float bf2f(unsigned short u) {
  unsigned int x = ((unsigned int)u) << 16;
  return __builtin_bit_cast(float, x);
}
__device__ __forceinline__ void store_c(unsigned short* p, float v) { *p = f2bf(v); }
__device__ __forceinline__ void store_c(float* p, float v) { *p = v; }

// ---------------- fp32 -> bf16 conversion for x, w_qkv, w_out in one launch ----------------
#define N4_X  (NB * SQ * DM / 4)
#define N4_WQ (3 * DM * DM / 4)
#define N4_WO (DM * DM / 4)
__global__ __launch_bounds__(256) void cvt_all(const float* __restrict__ x,
                                               const float* __restrict__ wq,
                                               const float* __restrict__ wo,
                                               unsigned short* __restrict__ x_b,
                                               unsigned short* __restrict__ wq_b,
                                               unsigned short* __restrict__ wo_b) {
  int i = blockIdx.x * blockDim.x + threadIdx.x;
  const float* src;
  unsigned short* dst;
  if (i < N4_X) {
    src = x; dst = x_b;
  } else if (i < N4_X + N4_WQ) {
    i -= N4_X; src = wq; dst = wq_b;
  } else {
    i -= N4_X + N4_WQ; src = wo; dst = wo_b;
  }
  const float4 v = ((const float4*)src)[i];
  ushort4 o;
  o.x = f2bf(v.x); o.y = f2bf(v.y); o.z = f2bf(v.z); o.w = f2bf(v.w);
  ((ushort4*)dst)[i] = o;
}

// ---------------- GEMM: C[M,N] = A[M,K] (bf16) @ W[N,K]^T (bf16) ----------------
// m97 structure: 128x128 tile, 4 waves, 4x4 16x16x32 MFMA, global_load_lds width=16.
template <typename OutT>
__global__ __launch_bounds__(256, 2) void gemm_bt(
    const unsigned short* __restrict__ A, const unsigned short* __restrict__ W,
    OutT* __restrict__ C, int M, int N, int K) {
  __shared__ __align__(16) unsigned short As[128 * 32];
  __shared__ __align__(16) unsigned short Ws[128 * 32];
  const int tid = threadIdx.x;
  const int lane = tid & 63;
  const int w = tid >> 6;
  const int wr = w >> 1, wc = w & 1;
  const int t16 = lane & 15, quad = lane >> 4;

  const long long rowA0 = (long long)blockIdx.y * 128;
  const long long colB0 = (long long)blockIdx.x * 128;
  const unsigned short* Abase = A + rowA0 * K;
  const unsigned short* Wbase = W + colB0 * K;

  const int c0 = tid, c1 = tid + 256;
  const int r0 = c0 >> 2, o0 = (c0 & 3) * 8;
  const int r1 = c1 >> 2, o1 = (c1 & 3) * 8;

  floatx4 acc[4][4] = {};

  for (int k0 = 0; k0 < K; k0 += 32) {
    __syncthreads();
    __builtin_amdgcn_global_load_lds(
        (const __attribute__((address_space(1))) void*)(Abase + (long long)r0 * K + k0 + o0),
        (__attribute__((address_space(3))) void*)(As + c0 * 8), 16, 0, 0);
    __builtin_amdgcn_global_load_lds(
        (const __attribute__((address_space(1))) void*)(Abase + (long long)r1 * K + k0 + o1),
        (__attribute__((address_space(3))) void*)(As + c1 * 8), 16, 0, 0);
    __builtin_amdgcn_global_load_lds(
        (const __attribute__((address_space(1))) void*)(Wbase + (long long)r0 * K + k0 + o0),
        (__attribute__((address_space(3))) void*)(Ws + c0 * 8), 16, 0, 0);
    __builtin_amdgcn_global_load_lds(
        (const __attribute__((address_space(1))) void*)(Wbase + (long long)r1 * K + k0 + o1),
        (__attribute__((address_space(3))) void*)(Ws + c1 * 8), 16, 0, 0);
    __syncthreads();

    short8 a[4], b[4];
#pragma unroll
    for (int i = 0; i < 4; i++)
      a[i] = *(const short8*)(As + (wr * 64 + i * 16 + t16) * 32 + quad * 8);
#pragma unroll
    for (int j = 0; j < 4; j++)
      b[j] = *(const short8*)(Ws + (wc * 64 + j * 16 + t16) * 32 + quad * 8);
#pragma unroll
    for (int i = 0; i < 4; i++)
#pragma unroll
      for (int j = 0; j < 4; j++)
        acc[i][j] = __builtin_amdgcn_mfma_f32_16x16x32_bf16(a[i], b[j], acc[i][j], 0, 0, 0);
  }

#pragma unroll
  for (int i = 0; i < 4; i++) {
    const int rt = wr * 64 + i * 16 + quad * 4;
#pragma unroll
    for (int j = 0; j < 4; j++) {
      const long long col = colB0 + wc * 64 + j * 16 + t16;
#pragma unroll
      for (int r = 0; r < 4; r++) {
        const long long row = rowA0 + rt + r;
        store_c(&C[row * N + col], acc[i][j][r]);
      }
    }
  }
}

// ---------------- RoPE + L2 norm + scale; Q,K only -> (B,H,S,HD) ----------------
__global__ __launch_bounds__(256) void rope_norm(
    const unsigned short* __restrict__ qkv, const float* __restrict__ freqs,
    const float* __restrict__ scale_p,
    unsigned short* __restrict__ Qn, unsigned short* __restrict__ Kn) {
  const int lane = threadIdx.x & 63;
  const int g = blockIdx.x * 4 + (threadIdx.x >> 6);  // b*32768 + s*16 + h
  const int h = g & 15;
  const int s = (g >> 4) & 2047;
  const int b = g >> 15;
  const float scale = *scale_p;

  const unsigned short* qp = qkv + ((long long)(b * SQ + s)) * QKV_N + h * HD + 2 * lane;
  const unsigned int q2 = *(const unsigned int*)(qp);
  const unsigned int k2 = *(const unsigned int*)(qp + DM);
  const float2 f2 = *(const float2*)(freqs + ((long long)s * 64 + lane) * 2);

  const float fc = f2.x, fs = f2.y;
  const float q0 = bf2f((unsigned short)(q2 & 0xffff)), q1 = bf2f((unsigned short)(q2 >> 16));
  const float k0 = bf2f((unsigned short)(k2 & 0xffff)), k1 = bf2f((unsigned short)(k2 >> 16));

  const float qr = q0 * fc - q1 * fs, qi = q0 * fs + q1 * fc;
  const float kr = k0 * fc - k1 * fs, ki = k0 * fs + k1 * fc;

  float sq = qr * qr + qi * qi;
  float sk = kr * kr + ki * ki;
#pragma unroll
  for (int m = 1; m < 64; m <<= 1) {
    sq += __shfl_xor(sq, m);
    sk += __shfl_xor(sk, m);
  }
  const float qs = scale / (sqrtf(sq) + 1e-6f);
  const float ks = 1.0f / (sqrtf(sk) + 1e-6f);

  const long long oidx = ((long long)(b * NH + h) * SQ + s) * HD + 2 * lane;
  *(unsigned int*)(Qn + oidx) = (unsigned int)f2bf(qr * qs) | ((unsigned int)f2bf(qi * qs) << 16);
  *(unsigned int*)(Kn + oidx) = (unsigned int)f2bf(kr * ks) | ((unsigned int)f2bf(ki * ks) << 16);
}

// ---------------- flash attention (causal), fixed-max softmax ----------------
// 128-thread blocks (2 waves, 16 q-rows each); block does 32-row band pair (j, 63-j)
// -> uniform 65 k-iters; 1024 blocks = 4/CU for latency hiding.
// V read directly from qkv (row stride QKV_N).
__global__ __launch_bounds__(128, 2) void attn(
    const unsigned short* __restrict__ Qn, const unsigned short* __restrict__ Kn,
    const unsigned short* __restrict__ qkv, const float* __restrict__ scale_p,
    unsigned short* __restrict__ Oout) {
  __shared__ __align__(16) unsigned short Ks[32 * 136];   // K rows, padded stride 136
  __shared__ __align__(16) unsigned short Vt[128 * 40];   // V transposed [d][key], stride 40
  __shared__ __align__(16) unsigned short Pw[2][16 * 40]; // per-wave P, stride 40

  const int tid = threadIdx.x;
  const int lane = tid & 63;
  const int w = tid >> 6;  // 0..1
  const int t16 = lane & 15, quad = lane >> 4;
  // XCD swizzle: k%8 = xcd; each xcd gets 4 consecutive heads (L2 locality)
  const int k = blockIdx.x;            // 0..1023
  const int xcd = k & 7, i = k >> 3;   // i 0..127
  const int bh = (xcd << 2) | (i & 3); // 0..31
  const int pj = i >> 2;               // 0..31: band pair (pj, 63-pj), 32-row bands
  const float M = *scale_p;
  const long long base = (long long)bh * SQ * HD;
  const int b = bh >> 4, h = bh & 15;
  const unsigned short* Vbase = qkv + 2 * DM + h * HD + (long long)b * SQ * QKV_N;
  unsigned short* pw = &Pw[w][0];

#pragma unroll
  for (int t = 0; t < 2; t++) {
    const int qb = (t == 0) ? 32 * pj : 32 * (63 - pj);

    // Q fragments (A layout: m=t16, k=quad*8+j)
    short8 qf[4];
    const int qrow = qb + w * 16 + t16;
#pragma unroll
    for (int c = 0; c < 4; c++)
      qf[c] = *(const short8*)(Qn + base + (long long)qrow * HD + c * 32 + quad * 8);

    floatx4 o[8] = {};
    float l[4] = {0.f, 0.f, 0.f, 0.f};
    const int qr0 = qb + w * 16 + quad * 4;  // C-layout row base
    const int kend = qb + 32;

    for (int kb = 0; kb < kend; kb += 32) {
      __syncthreads();
      // stage K tile rows [kb, kb+32), padded stride 136 (128 threads x 4 chunks)
#pragma unroll
      for (int cc = 0; cc < 4; cc++) {
        const int c = tid + cc * 128;
        const int row = c >> 4, off = (c & 15) * 8;
        const uint4 d = *(const uint4*)(Kn + base + (long long)(kb + row) * HD + off);
        *(uint4*)(Ks + row * 136 + off) = d;
      }
      // stage V transposed from qkv (row stride QKV_N): 128 threads x 2 pack-units
#pragma unroll
      for (int cc = 0; cc < 2; cc++) {
        const int idx = tid + cc * 128;
        const int kk0 = (idx & 15) * 2;
        const int d0 = (idx >> 4) * 8;
        const unsigned short* vp = Vbase + (long long)(kb + kk0) * QKV_N + d0;
        const short8 v0 = *(const short8*)(vp);
        const short8 v1 = *(const short8*)(vp + QKV_N);
#pragma unroll
        for (int jj = 0; jj < 8; jj++) {
          const unsigned int pk = (unsigned int)(unsigned short)v0[jj] |
                                  ((unsigned int)(unsigned short)v1[jj] << 16);
          *(unsigned int*)(Vt + (d0 + jj) * 40 + kk0) = pk;
        }
      }
      __syncthreads();

      // scores: 16 q x 32 keys, fp32 accum
      floatx4 sc0 = {}, sc1 = {};
#pragma unroll
      for (int c = 0; c < 4; c++) {
        const short8 kf0 = *(const short8*)(Ks + t16 * 136 + c * 32 + quad * 8);
        const short8 kf1 = *(const short8*)(Ks + (16 + t16) * 136 + c * 32 + quad * 8);
        sc0 = __builtin_amdgcn_mfma_f32_16x16x32_bf16(qf[c], kf0, sc0, 0, 0, 0);
        sc1 = __builtin_amdgcn_mfma_f32_16x16x32_bf16(qf[c], kf1, sc1, 0, 0, 0);
      }
      // fixed-max softmax (scores <= M by construction) + causal mask -> p, l
#pragma unroll
      for (int r = 0; r < 4; r++) {
        float e0 = __expf(sc0[r] - M);
        float e1 = __expf(sc1[r] - M);
        e0 = (kb + t16 <= qr0 + r) ? e0 : 0.f;
        e1 = (kb + 16 + t16 <= qr0 + r) ? e1 : 0.f;
        l[r] += e0 + e1;
        pw[(quad * 4 + r) * 40 + t16] = f2bf(e0);
        pw[(quad * 4 + r) * 40 + 16 + t16] = f2bf(e1);
      }
      asm volatile("s_waitcnt lgkmcnt(0)" ::: "memory");  // same-wave LDS WAR/RAW fence
      const short8 pf = *(const short8*)(pw + t16 * 40 + quad * 8);
      // PV: B frag from Vt is contiguous 16B per lane
#pragma unroll
      for (int dc = 0; dc < 8; dc++) {
        const short8 vf = *(const short8*)(Vt + (dc * 16 + t16) * 40 + quad * 8);
        o[dc] = __builtin_amdgcn_mfma_f32_16x16x32_bf16(pf, vf, o[dc], 0, 0, 0);
      }
    }

    // l: reduce across the 16 lanes of the quad-row group, then epilogue
    float linv[4];
#pragma unroll
    for (int r = 0; r < 4; r++) {
      float s = l[r];
      s += __shfl_xor(s, 1);
      s += __shfl_xor(s, 2);
      s += __shfl_xor(s, 4);
      s += __shfl_xor(s, 8);
      linv[r] = 1.0f / s;
    }
#pragma unroll
    for (int dc = 0; dc < 8; dc++)
#pragma unroll
      for (int r = 0; r < 4; r++) {
        const int q = qb + w * 16 + quad * 4 + r;
        Oout[(long long)(b * SQ + q) * DM + h * HD + dc * 16 + t16] =
            f2bf(o[dc][r] * linv[r]);
      }
  }
}

extern "C" void kernel_launch(void* const* d_in, const int* in_sizes, int n_in,
                              void* d_out, int out_size, void* d_ws, size_t ws_size,
                              hipStream_t stream) {
  const float* x = (const float*)d_in[0];
  const float* freqs = (const float*)d_in[1];
  const float* w_qkv = (const float*)d_in[2];
  const float* w_out = (const float*)d_in[3];
  const float* attn_scale = (const float*)d_in[4];
  float* out = (float*)d_out;

  char* ws = (char*)d_ws;
  // [0, 50331648)          qkv bf16 4096x6144 (live through attn: V read in-place)
  // [50331648, +16M each)  Qn / Kn bf16 (B,H,S,HD)
  // [100663296, +16M)      x_b bf16 (dead after gemm1; re-used as attn_o)
  // [117440512, +25M)      w_qkv_b
  // [142606336, +8M)       w_out_b
  unsigned short* qkv = (unsigned short*)ws;
  unsigned short* Qn = (unsigned short*)(ws + 50331648);
  unsigned short* Kn = Qn + (size_t)NB * NH * SQ * HD;
  unsigned short* x_b = (unsigned short*)(ws + 100663296);
  unsigned short* attn_o = x_b;  // alias: x_b dead after gemm1
  unsigned short* w_qkv_b = (unsigned short*)(ws + 117440512);
  unsigned short* w_out_b = (unsigned short*)(ws + 142606336);

  cvt_all<<<dim3((N4_X + N4_WQ + N4_WO + 255) / 256), 256, 0, stream>>>(
      x, w_qkv, w_out, x_b, w_qkv_b, w_out_b);

  gemm_bt<unsigned short><<<dim3(QKV_N / 128, (NB * SQ) / 128), 256, 0, stream>>>(
      x_b, w_qkv_b, qkv, NB * SQ, QKV_N, DM);
  rope_norm<<<dim3((NB * SQ * NH) / 4), 256, 0, stream>>>(qkv, freqs, attn_scale, Qn, Kn);
  attn<<<dim3(1024), 128, 0, stream>>>(Qn, Kn, qkv, attn_scale, attn_o);
  gemm_bt<float><<<dim3(DM / 128, (NB * SQ) / 128), 256, 0, stream>>>(
      attn_o, w_out_b, out, NB * SQ, DM, DM);
}

// Round 7
// 408.182 us; speedup vs baseline: 1.0774x; 1.0774x over previous
//
#include <hip/hip_runtime.h>
#include <math.h>

typedef __attribute__((ext_vector_type(8))) short short8;
typedef __attribute__((ext_vector_type(4))) float floatx4;

#define SQ 2048
#define NH 16
#define HD 128
#define NB 2
#define DM 2048
#define QKV_N 6144

__device__ __forceinline__ unsigned short f2bf(float f) {
  unsigned int x = __builtin_bit_cast(unsigned int, f);
  unsigned int r = x + 0x7fffu + ((x >> 16) & 1u);
  return (unsigned short)(r >> 16);
}
__device__ __forceinline__ float bf2f(unsigned short u) {
  unsigned int x = ((unsigned int)u) << 16;
  return __builtin_bit_cast(float, x);
}
__device__ __forceinline__ void store_c(unsigned short* p, float v) { *p = f2bf(v); }
__device__ __forceinline__ void store_c(float* p, float v) { *p = v; }

// ---------------- fp32 -> bf16 conversion for x, w_qkv, w_out in one launch ----------------
#define N4_X  (NB * SQ * DM / 4)
#define N4_WQ (3 * DM * DM / 4)
#define N4_WO (DM * DM / 4)
__global__ __launch_bounds__(256) void cvt_all(const float* __restrict__ x,
                                               const float* __restrict__ wq,
                                               const float* __restrict__ wo,
                                               unsigned short* __restrict__ x_b,
                                               unsigned short* __restrict__ wq_b,
                                               unsigned short* __restrict__ wo_b) {
  int i = blockIdx.x * blockDim.x + threadIdx.x;
  const float* src;
  unsigned short* dst;
  if (i < N4_X) {
    src = x; dst = x_b;
  } else if (i < N4_X + N4_WQ) {
    i -= N4_X; src = wq; dst = wq_b;
  } else {
    i -= N4_X + N4_WQ; src = wo; dst = wo_b;
  }
  const float4 v = ((const float4*)src)[i];
  ushort4 o;
  o.x = f2bf(v.x); o.y = f2bf(v.y); o.z = f2bf(v.z); o.w = f2bf(v.w);
  ((ushort4*)dst)[i] = o;
}

// ---------------- GEMM: C[M,N] = A[M,K] (bf16) @ W[N,K]^T (bf16) ----------------
// m97 structure: 128x128 tile, 4 waves, 4x4 16x16x32 MFMA, global_load_lds width=16.
template <typename OutT>
__global__ __launch_bounds__(256, 2) void gemm_bt(
    const unsigned short* __restrict__ A, const unsigned short* __restrict__ W,
    OutT* __restrict__ C, int M, int N, int K) {
  __shared__ __align__(16) unsigned short As[128 * 32];
  __shared__ __align__(16) unsigned short Ws[128 * 32];
  const int tid = threadIdx.x;
  const int lane = tid & 63;
  const int w = tid >> 6;
  const int wr = w >> 1, wc = w & 1;
  const int t16 = lane & 15, quad = lane >> 4;

  const long long rowA0 = (long long)blockIdx.y * 128;
  const long long colB0 = (long long)blockIdx.x * 128;
  const unsigned short* Abase = A + rowA0 * K;
  const unsigned short* Wbase = W + colB0 * K;

  const int c0 = tid, c1 = tid + 256;
  const int r0 = c0 >> 2, o0 = (c0 & 3) * 8;
  const int r1 = c1 >> 2, o1 = (c1 & 3) * 8;

  floatx4 acc[4][4] = {};

  for (int k0 = 0; k0 < K; k0 += 32) {
    __syncthreads();
    __builtin_amdgcn_global_load_lds(
        (const __attribute__((address_space(1))) void*)(Abase + (long long)r0 * K + k0 + o0),
        (__attribute__((address_space(3))) void*)(As + c0 * 8), 16, 0, 0);
    __builtin_amdgcn_global_load_lds(
        (const __attribute__((address_space(1))) void*)(Abase + (long long)r1 * K + k0 + o1),
        (__attribute__((address_space(3))) void*)(As + c1 * 8), 16, 0, 0);
    __builtin_amdgcn_global_load_lds(
        (const __attribute__((address_space(1))) void*)(Wbase + (long long)r0 * K + k0 + o0),
        (__attribute__((address_space(3))) void*)(Ws + c0 * 8), 16, 0, 0);
    __builtin_amdgcn_global_load_lds(
        (const __attribute__((address_space(1))) void*)(Wbase + (long long)r1 * K + k0 + o1),
        (__attribute__((address_space(3))) void*)(Ws + c1 * 8), 16, 0, 0);
    __syncthreads();

    short8 a[4], b[4];
#pragma unroll
    for (int i = 0; i < 4; i++)
      a[i] = *(const short8*)(As + (wr * 64 + i * 16 + t16) * 32 + quad * 8);
#pragma unroll
    for (int j = 0; j < 4; j++)
      b[j] = *(const short8*)(Ws + (wc * 64 + j * 16 + t16) * 32 + quad * 8);
#pragma unroll
    for (int i = 0; i < 4; i++)
#pragma unroll
      for (int j = 0; j < 4; j++)
        acc[i][j] = __builtin_amdgcn_mfma_f32_16x16x32_bf16(a[i], b[j], acc[i][j], 0, 0, 0);
  }

#pragma unroll
  for (int i = 0; i < 4; i++) {
    const int rt = wr * 64 + i * 16 + quad * 4;
#pragma unroll
    for (int j = 0; j < 4; j++) {
      const long long col = colB0 + wc * 64 + j * 16 + t16;
#pragma unroll
      for (int r = 0; r < 4; r++) {
        const long long row = rowA0 + rt + r;
        store_c(&C[row * N + col], acc[i][j][r]);
      }
    }
  }
}

// ---------------- RoPE + L2 norm + scale; Q,K only -> (B,H,S,HD) ----------------
__global__ __launch_bounds__(256) void rope_norm(
    const unsigned short* __restrict__ qkv, const float* __restrict__ freqs,
    const float* __restrict__ scale_p,
    unsigned short* __restrict__ Qn, unsigned short* __restrict__ Kn) {
  const int lane = threadIdx.x & 63;
  const int g = blockIdx.x * 4 + (threadIdx.x >> 6);  // b*32768 + s*16 + h
  const int h = g & 15;
  const int s = (g >> 4) & 2047;
  const int b = g >> 15;
  const float scale = *scale_p;

  const unsigned short* qp = qkv + ((long long)(b * SQ + s)) * QKV_N + h * HD + 2 * lane;
  const unsigned int q2 = *(const unsigned int*)(qp);
  const unsigned int k2 = *(const unsigned int*)(qp + DM);
  const float2 f2 = *(const float2*)(freqs + ((long long)s * 64 + lane) * 2);

  const float fc = f2.x, fs = f2.y;
  const float q0 = bf2f((unsigned short)(q2 & 0xffff)), q1 = bf2f((unsigned short)(q2 >> 16));
  const float k0 = bf2f((unsigned short)(k2 & 0xffff)), k1 = bf2f((unsigned short)(k2 >> 16));

  const float qr = q0 * fc - q1 * fs, qi = q0 * fs + q1 * fc;
  const float kr = k0 * fc - k1 * fs, ki = k0 * fs + k1 * fc;

  float sq = qr * qr + qi * qi;
  float sk = kr * kr + ki * ki;
#pragma unroll
  for (int m = 1; m < 64; m <<= 1) {
    sq += __shfl_xor(sq, m);
    sk += __shfl_xor(sk, m);
  }
  const float qs = scale / (sqrtf(sq) + 1e-6f);
  const float ks = 1.0f / (sqrtf(sk) + 1e-6f);

  const long long oidx = ((long long)(b * NH + h) * SQ + s) * HD + 2 * lane;
  *(unsigned int*)(Qn + oidx) = (unsigned int)f2bf(qr * qs) | ((unsigned int)f2bf(qi * qs) << 16);
  *(unsigned int*)(Kn + oidx) = (unsigned int)f2bf(kr * ks) | ((unsigned int)f2bf(ki * ks) << 16);
}

// ---------------- flash attention (causal), fixed-max softmax, 64-key blocks ----------------
// 256-thread blocks (4 waves x 16 q-rows = 64-row band); band pair (pb, 31-pb)
// -> uniform 33 x 64-key iterations; 512 blocks = 2/CU.
// V read directly from qkv (row stride QKV_N).
__global__ __launch_bounds__(256, 2) void attn(
    const unsigned short* __restrict__ Qn, const unsigned short* __restrict__ Kn,
    const unsigned short* __restrict__ qkv, const float* __restrict__ scale_p,
    unsigned short* __restrict__ Oout) {
  __shared__ __align__(16) unsigned short Ks[64 * 136];   // K rows, padded stride 136
  __shared__ __align__(16) unsigned short Vt[128 * 72];   // V transposed [d][key], stride 72
  __shared__ __align__(16) unsigned short Pw[4][16 * 72]; // per-wave P, stride 72

  const int tid = threadIdx.x;
  const int lane = tid & 63;
  const int w = tid >> 6;
  const int t16 = lane & 15, quad = lane >> 4;
  // XCD swizzle: k%8 = xcd; each xcd gets 4 consecutive heads (L2 locality)
  const int k = blockIdx.x;            // 0..511
  const int xcd = k & 7, i = k >> 3;   // i 0..63
  const int bh = (xcd << 2) | (i & 3); // 0..31
  const int pb = i >> 2;               // 0..15: band pair (pb, 31-pb), 64-row bands
  const float M = *scale_p;
  const long long base = (long long)bh * SQ * HD;
  const int b = bh >> 4, h = bh & 15;
  const unsigned short* Vbase = qkv + 2 * DM + h * HD + (long long)b * SQ * QKV_N;
  unsigned short* pw = &Pw[w][0];

#pragma unroll
  for (int t = 0; t < 2; t++) {
    const int qb = (t == 0) ? 64 * pb : 64 * (31 - pb);

    // Q fragments (A layout: m=t16, k=quad*8+j)
    short8 qf[4];
    const int qrow = qb + w * 16 + t16;
#pragma unroll
    for (int c = 0; c < 4; c++)
      qf[c] = *(const short8*)(Qn + base + (long long)qrow * HD + c * 32 + quad * 8);

    floatx4 o[8] = {};
    float l[4] = {0.f, 0.f, 0.f, 0.f};
    const int qr0 = qb + w * 16 + quad * 4;  // C-layout row base
    const int kend = qb + 64;

    for (int kb = 0; kb < kend; kb += 64) {
      __syncthreads();
      // stage K rows [kb, kb+64), padded stride 136 (256 threads x 4 uint4)
#pragma unroll
      for (int cc = 0; cc < 4; cc++) {
        const int c = tid + cc * 256;
        const int row = c >> 4, off = (c & 15) * 8;
        const uint4 d = *(const uint4*)(Kn + base + (long long)(kb + row) * HD + off);
        *(uint4*)(Ks + row * 136 + off) = d;
      }
      // stage V transposed from qkv (row stride QKV_N): 256 threads x 2 pack-units
#pragma unroll
      for (int cc = 0; cc < 2; cc++) {
        const int idx = tid + cc * 256;
        const int kk0 = (idx & 31) * 2;     // key pair 0..62
        const int d0 = (idx >> 5) * 8;      // dim group 0..120
        const unsigned short* vp = Vbase + (long long)(kb + kk0) * QKV_N + d0;
        const short8 v0 = *(const short8*)(vp);
        const short8 v1 = *(const short8*)(vp + QKV_N);
#pragma unroll
        for (int jj = 0; jj < 8; jj++) {
          const unsigned int pk = (unsigned int)(unsigned short)v0[jj] |
                                  ((unsigned int)(unsigned short)v1[jj] << 16);
          *(unsigned int*)(Vt + (d0 + jj) * 72 + kk0) = pk;
        }
      }
      __syncthreads();

      // scores: 16 q x 64 keys, fp32 accum
      floatx4 sc[4];
#pragma unroll
      for (int g = 0; g < 4; g++) {
        floatx4 s = {};
        const unsigned short* kr = Ks + (g * 16 + t16) * 136 + quad * 8;
#pragma unroll
        for (int c = 0; c < 4; c++)
          s = __builtin_amdgcn_mfma_f32_16x16x32_bf16(qf[c], *(const short8*)(kr + c * 32), s, 0, 0, 0);
        sc[g] = s;
      }
      // fixed-max softmax (scores <= M by construction) + causal mask -> p, l
#pragma unroll
      for (int r = 0; r < 4; r++) {
        const int qr = qr0 + r;
        float e[4];
#pragma unroll
        for (int g = 0; g < 4; g++) {
          float ee = __expf(sc[g][r] - M);
          e[g] = (kb + g * 16 + t16 <= qr) ? ee : 0.f;
        }
        l[r] += (e[0] + e[1]) + (e[2] + e[3]);
#pragma unroll
        for (int g = 0; g < 4; g++)
          pw[(quad * 4 + r) * 72 + g * 16 + t16] = f2bf(e[g]);
      }
      asm volatile("s_waitcnt lgkmcnt(0)" ::: "memory");  // same-wave LDS RAW fence
      const short8 pf0 = *(const short8*)(pw + t16 * 72 + quad * 8);
      const short8 pf1 = *(const short8*)(pw + t16 * 72 + 32 + quad * 8);
      // PV over both 32-key halves: B frags contiguous 16B per lane from Vt
#pragma unroll
      for (int dc = 0; dc < 8; dc++) {
        const unsigned short* vc = Vt + (dc * 16 + t16) * 72;
        o[dc] = __builtin_amdgcn_mfma_f32_16x16x32_bf16(pf0, *(const short8*)(vc + quad * 8), o[dc], 0, 0, 0);
        o[dc] = __builtin_amdgcn_mfma_f32_16x16x32_bf16(pf1, *(const short8*)(vc + 32 + quad * 8), o[dc], 0, 0, 0);
      }
    }

    // l: reduce across the 16 lanes of the quad-row group, then epilogue
    float linv[4];
#pragma unroll
    for (int r = 0; r < 4; r++) {
      float s = l[r];
      s += __shfl_xor(s, 1);
      s += __shfl_xor(s, 2);
      s += __shfl_xor(s, 4);
      s += __shfl_xor(s, 8);
      linv[r] = 1.0f / s;
    }
#pragma unroll
    for (int dc = 0; dc < 8; dc++)
#pragma unroll
      for (int r = 0; r < 4; r++) {
        const int q = qb + w * 16 + quad * 4 + r;
        Oout[(long long)(b * SQ + q) * DM + h * HD + dc * 16 + t16] =
            f2bf(o[dc][r] * linv[r]);
      }
  }
}

extern "C" void kernel_launch(void* const* d_in, const int* in_sizes, int n_in,
                              void* d_out, int out_size, void* d_ws, size_t ws_size,
                              hipStream_t stream) {
  const float* x = (const float*)d_in[0];
  const float* freqs = (const float*)d_in[1];
  const float* w_qkv = (const float*)d_in[2];
  const float* w_out = (const float*)d_in[3];
  const float* attn_scale = (const float*)d_in[4];
  float* out = (float*)d_out;

  char* ws = (char*)d_ws;
  // [0, 50331648)          qkv bf16 4096x6144 (live through attn: V read in-place)
  // [50331648, +16M each)  Qn / Kn bf16 (B,H,S,HD)
  // [100663296, +16M)      x_b bf16 (dead after gemm1; re-used as attn_o)
  // [117440512, +25M)      w_qkv_b
  // [142606336, +8M)       w_out_b
  unsigned short* qkv = (unsigned short*)ws;
  unsigned short* Qn = (unsigned short*)(ws + 50331648);
  unsigned short* Kn = Qn + (size_t)NB * NH * SQ * HD;
  unsigned short* x_b = (unsigned short*)(ws + 100663296);
  unsigned short* attn_o = x_b;  // alias: x_b dead after gemm1
  unsigned short* w_qkv_b = (unsigned short*)(ws + 117440512);
  unsigned short* w_out_b = (unsigned short*)(ws + 142606336);

  cvt_all<<<dim3((N4_X + N4_WQ + N4_WO + 255) / 256), 256, 0, stream>>>(
      x, w_qkv, w_out, x_b, w_qkv_b, w_out_b);

  gemm_bt<unsigned short><<<dim3(QKV_N / 128, (NB * SQ) / 128), 256, 0, stream>>>(
      x_b, w_qkv_b, qkv, NB * SQ, QKV_N, DM);
  rope_norm<<<dim3((NB * SQ * NH) / 4), 256, 0, stream>>>(qkv, freqs, attn_scale, Qn, Kn);
  attn<<<dim3(512), 256, 0, stream>>>(Qn, Kn, qkv, attn_scale, attn_o);
  gemm_bt<float><<<dim3(DM / 128, (NB * SQ) / 128), 256, 0, stream>>>(
      attn_o, w_out_b, out, NB * SQ, DM, DM);
}